// Round 1
// baseline (71.829 us; speedup 1.0000x reference)
//
#include <hip/hip_runtime.h>
#include <float.h>

#define N_NODES_C 200000
#define HIDDEN_C 256
#define NSEG_C 1024
#define NEG_SLOPE_C 0.2f
#define CHUNK_C 1024

__device__ __forceinline__ int lower_bound_dev(const int* __restrict__ b, int n, int v) {
    int lo = 0, hi = n;
    while (lo < hi) {
        int mid = (lo + hi) >> 1;
        if (b[mid] < v) lo = mid + 1; else hi = mid;
    }
    return lo;
}

__global__ __launch_bounds__(256, 4)
void attn_pool_kernel(const float* __restrict__ feature,
                      const float* __restrict__ a,
                      const int* __restrict__ batch,
                      float* __restrict__ out) {
    const int s    = blockIdx.x;
    const int tid  = threadIdx.x;
    const int lane = tid & 63;
    const int wid  = tid >> 6;

    __shared__ float logits[CHUNK_C];
    __shared__ float red[8];
    __shared__ float part[4][HIDDEN_C];

    // Segment bounds: batch is sorted, contiguous range of rows.
    const int s0 = lower_bound_dev(batch, N_NODES_C, s);
    const int s1 = lower_bound_dev(batch, N_NODES_C, s + 1);
    const int cnt = s1 - s0;

    if (cnt == 0) {
        out[(size_t)s * HIDDEN_C + tid] = 0.0f;
        return;
    }

    // Each lane owns a[4*lane .. 4*lane+3] for the dot product.
    const float4 av = *reinterpret_cast<const float4*>(a + 4 * lane);

    float  m_run = -FLT_MAX;   // running max (uniform across threads)
    float  d_run = 0.0f;       // running exp-sum (uniform across threads)
    float4 acc   = make_float4(0.f, 0.f, 0.f, 0.f);  // per-thread partial of 4 cols

    for (int c0 = s0; c0 < s1; c0 += CHUNK_C) {
        const int c1   = (c0 + CHUNK_C < s1) ? (c0 + CHUNK_C) : s1;
        const int clen = c1 - c0;

        // ---- Pass A: logits for this chunk. One row per wave per step. ----
        for (int i = c0 + wid; i < c1; i += 4) {
            const float4 f = *reinterpret_cast<const float4*>(
                feature + (size_t)i * HIDDEN_C + 4 * lane);
            float p = f.x * av.x + f.y * av.y + f.z * av.z + f.w * av.w;
            #pragma unroll
            for (int off = 32; off >= 1; off >>= 1)
                p += __shfl_xor(p, off, 64);
            if (lane == 0) {
                const float l = (p > 0.0f) ? p : NEG_SLOPE_C * p;
                logits[i - c0] = l;
            }
        }
        __syncthreads();

        // ---- Chunk max (block reduction). ----
        float cm = -FLT_MAX;
        for (int j = tid; j < clen; j += 256) cm = fmaxf(cm, logits[j]);
        #pragma unroll
        for (int off = 32; off >= 1; off >>= 1)
            cm = fmaxf(cm, __shfl_xor(cm, off, 64));
        if (lane == 0) red[wid] = cm;
        __syncthreads();
        cm = fmaxf(fmaxf(red[0], red[1]), fmaxf(red[2], red[3]));

        const float m_new = fmaxf(m_run, cm);
        const float scale = __expf(m_run - m_new);  // 0 on first chunk (exp(-inf))
        acc.x *= scale; acc.y *= scale; acc.z *= scale; acc.w *= scale;
        d_run *= scale;
        m_run  = m_new;

        // ---- Pass C: weighted accumulate. Wave wid handles rows c0+wid :: 4.
        // Rows were just read in pass A by this same block -> L2/L3 hits. ----
        float wsum = 0.0f;
        for (int i = c0 + wid; i < c1; i += 4) {
            const float w = __expf(logits[i - c0] - m_new);  // LDS broadcast read
            wsum += w;
            const float4 f = *reinterpret_cast<const float4*>(
                feature + (size_t)i * HIDDEN_C + 4 * lane);
            acc.x += w * f.x;
            acc.y += w * f.y;
            acc.z += w * f.z;
            acc.w += w * f.w;
        }
        // wsum is identical across the 64 lanes of a wave.
        if (lane == 0) red[4 + wid] = wsum;
        __syncthreads();
        d_run += red[4] + red[5] + red[6] + red[7];
        // (next chunk's pass-A logits writes are fenced by the sync above
        //  plus the sync after pass A)
    }

    // ---- Combine the 4 row-group partials and write out. ----
    *reinterpret_cast<float4*>(&part[wid][4 * lane]) = acc;
    __syncthreads();
    const float v = part[0][tid] + part[1][tid] + part[2][tid] + part[3][tid];
    const float inv = 1.0f / (d_run * (float)cnt);
    out[(size_t)s * HIDDEN_C + tid] = v * inv;
}

extern "C" void kernel_launch(void* const* d_in, const int* in_sizes, int n_in,
                              void* d_out, int out_size, void* d_ws, size_t ws_size,
                              hipStream_t stream) {
    const float* feature = (const float*)d_in[0];
    const float* a       = (const float*)d_in[1];
    const int*   batch   = (const int*)d_in[2];
    float* out = (float*)d_out;
    (void)in_sizes; (void)n_in; (void)out_size; (void)d_ws; (void)ws_size;

    attn_pool_kernel<<<NSEG_C, 256, 0, stream>>>(feature, a, batch, out);
}

// Round 2
// 45.765 us; speedup vs baseline: 1.5695x; 1.5695x over previous
//
#include <hip/hip_runtime.h>
#include <float.h>

#define N_NODES_C 200000
#define HIDDEN_C 256
#define NSEG_C 1024
#define NEG_SLOPE_C 0.2f

__device__ __forceinline__ int lower_bound_dev(const int* __restrict__ b, int n, int v) {
    int lo = 0, hi = n;
    while (lo < hi) {
        int mid = (lo + hi) >> 1;
        if (b[mid] < v) lo = mid + 1; else hi = mid;
    }
    return lo;
}

__global__ __launch_bounds__(256, 4)
void attn_pool_1pass(const float* __restrict__ feature,
                     const float* __restrict__ a,
                     const int* __restrict__ batch,
                     float* __restrict__ out) {
    const int s    = blockIdx.x;
    const int tid  = threadIdx.x;
    const int lane = tid & 63;
    const int wid  = tid >> 6;

    __shared__ float part[4][HIDDEN_C];
    __shared__ float md[4][2];   // per-wave {max, denom}

    const int s0  = lower_bound_dev(batch, N_NODES_C, s);
    const int s1  = lower_bound_dev(batch, N_NODES_C, s + 1);
    const int cnt = s1 - s0;

    if (cnt == 0) {
        out[(size_t)s * HIDDEN_C + tid] = 0.0f;
        return;
    }

    // Lane owns columns 4*lane .. 4*lane+3.
    const float4 av = *reinterpret_cast<const float4*>(a + 4 * lane);

    // Per-wave online softmax state (m, d uniform across the wave's lanes).
    float  m   = -FLT_MAX;
    float  d   = 0.0f;
    float4 acc = make_float4(0.f, 0.f, 0.f, 0.f);

    // dot(feature_row, a) + leaky_relu; butterfly gives every lane the total.
    auto dotred = [&](const float4& f) -> float {
        float p = f.x * av.x + f.y * av.y + f.z * av.z + f.w * av.w;
        #pragma unroll
        for (int off = 32; off >= 1; off >>= 1)
            p += __shfl_xor(p, off, 64);
        return (p > 0.0f) ? p : NEG_SLOPE_C * p;
    };

    // Exact online-softmax update with the row still in registers.
    auto online = [&](float l, const float4& f) {
        if (l > m) {                    // wave-uniform branch
            const float sc = __expf(m - l);   // exp(-inf)=0 on first row
            acc.x = acc.x * sc + f.x;
            acc.y = acc.y * sc + f.y;
            acc.z = acc.z * sc + f.z;
            acc.w = acc.w * sc + f.w;
            d = d * sc + 1.0f;
            m = l;
        } else {
            const float w = __expf(l - m);
            acc.x += w * f.x;
            acc.y += w * f.y;
            acc.z += w * f.z;
            acc.w += w * f.w;
            d += w;
        }
    };

    // Wave wid handles rows s0+wid :: 4. 2-row unroll for load/shuffle ILP.
    int i = s0 + wid;
    for (; i + 4 < s1; i += 8) {
        const float4 f0 = *reinterpret_cast<const float4*>(
            feature + (size_t)i * HIDDEN_C + 4 * lane);
        const float4 f1 = *reinterpret_cast<const float4*>(
            feature + (size_t)(i + 4) * HIDDEN_C + 4 * lane);
        const float l0 = dotred(f0);
        const float l1 = dotred(f1);
        online(l0, f0);
        online(l1, f1);
    }
    if (i < s1) {
        const float4 f0 = *reinterpret_cast<const float4*>(
            feature + (size_t)i * HIDDEN_C + 4 * lane);
        online(dotred(f0), f0);
    }

    // ---- Exact merge of the 4 wave partials. ----
    *reinterpret_cast<float4*>(&part[wid][4 * lane]) = acc;
    if (lane == 0) { md[wid][0] = m; md[wid][1] = d; }
    __syncthreads();

    const float M  = fmaxf(fmaxf(md[0][0], md[1][0]), fmaxf(md[2][0], md[3][0]));
    const float e0 = __expf(md[0][0] - M);
    const float e1 = __expf(md[1][0] - M);
    const float e2 = __expf(md[2][0] - M);
    const float e3 = __expf(md[3][0] - M);
    const float D  = e0 * md[0][1] + e1 * md[1][1] + e2 * md[2][1] + e3 * md[3][1];

    const float v = e0 * part[0][tid] + e1 * part[1][tid]
                  + e2 * part[2][tid] + e3 * part[3][tid];
    out[(size_t)s * HIDDEN_C + tid] = v / (D * (float)cnt);
}

extern "C" void kernel_launch(void* const* d_in, const int* in_sizes, int n_in,
                              void* d_out, int out_size, void* d_ws, size_t ws_size,
                              hipStream_t stream) {
    const float* feature = (const float*)d_in[0];
    const float* a       = (const float*)d_in[1];
    const int*   batch   = (const int*)d_in[2];
    float* out = (float*)d_out;
    (void)in_sizes; (void)n_in; (void)out_size; (void)d_ws; (void)ws_size;

    attn_pool_1pass<<<NSEG_C, 256, 0, stream>>>(feature, a, batch, out);
}